// Round 7
// baseline (55533.203 us; speedup 1.0000x reference)
//
#include <hip/hip_runtime.h>
#include <math.h>

// ---------------------------------------------------------------------------
// LSTM_FEAT_2: T=4096 sequential 2-layer LSTM + log-softmax feedback.
// R7: 256 wgs x 512 thr (1 wg/CU FORCED by 133KB LDS -> residency guaranteed,
// fixes R6 deadlock). Weights: 88 f/thread pinned regs (under the proven
// 128-VGPR cap) + 120KB/wg in LDS. 2 barriers/step. WCL fold computed
// in-kernel at init; ws shrunk to 8.8MB (R1-R5 proved >=16MB available).
//
// Math:
//   feat_t = Ws@x_t + bs                       (startup kernel)
//   Wih1e@embed = WCL@h2 + biasE2 - rsWC*lse,  WCL=(Wih1e@Wm)@Wl,
//     biasE2 = Wih1e@bm + WC@bl, rsWC=rowsum(WC), WC=Wih1e@Wm
//   gates1 = [Wih1s|Whh1]@[feat;h1] + WCL@h2 + biasA [+ biasE2 - rsWC*lse]
//   gates2 = [Wih2|Whh2]@[h1;h2] + biasB
//   y_t    = Wl@h2_t + bl  -> d_out ; post-pass: out = log_softmax(out)
// ---------------------------------------------------------------------------

#define T_STEPS 4096
#define NWG 256

// ws layout (bytes)
#define WS_ML1    0            // 16 pages x 32KB (main barrier L1; 8192 slots)
#define ML1_PAGE  32768
#define WS_MROOT  524288       // 32KB (8192 slots)
#define WS_YL1    557056       // 16 pages x 16KB (y counter; 4096 slots)
#define YL1_PAGE  16384
#define WS_YROOT  819200       // 16KB
#define WS_H1     835584       // float[2][1024]
#define WS_H2     843776       // float[2][1024]
#define WS_ZERO_BYTES 851968
#define WS_FEAT   851968       // float[4096][512] -> end 9,240,576 (~8.8MB)

// dynamic LDS partition (floats)
#define OFF_WA 2560            // s_in[2560] | wa[16][1024] | wb[16][768] | wy[2][1024]
#define OFF_WB 18944
#define OFF_WY 31232
#define SMEM_FLOATS 33280
#define SMEM_BYTES  (SMEM_FLOATS*4)

#define PIN4(v) asm volatile("" : "+v"((v).x), "+v"((v).y), "+v"((v).z), "+v"((v).w))
#define PIN1(v) asm volatile("" : "+v"(v))
#define FMA4(acc,s,v4) {(acc).x += (s)*(v4).x; (acc).y += (s)*(v4).y; (acc).z += (s)*(v4).z; (acc).w += (s)*(v4).w;}
#define DOT4(a,b) ((a).x*(b).x + (a).y*(b).y + (a).z*(b).z + (a).w*(b).w)

__device__ __forceinline__ float AL(const float* p){
  return __hip_atomic_load(p, __ATOMIC_RELAXED, __HIP_MEMORY_SCOPE_AGENT);
}
__device__ __forceinline__ float2 AL2(const float* p){
  unsigned long long u = __hip_atomic_load((const unsigned long long*)p,
                                           __ATOMIC_RELAXED, __HIP_MEMORY_SCOPE_AGENT);
  union { unsigned long long u; float2 f; } c; c.u = u; return c.f;
}
__device__ __forceinline__ void AS(float* p, float v){
  __hip_atomic_store(p, v, __ATOMIC_RELAXED, __HIP_MEMORY_SCOPE_AGENT);
}
__device__ __forceinline__ unsigned AU_LD(const unsigned* p){
  return __hip_atomic_load(p, __ATOMIC_RELAXED, __HIP_MEMORY_SCOPE_AGENT);
}
__device__ __forceinline__ unsigned AU_ADD(unsigned* p){
  return __hip_atomic_fetch_add(p, 1u, __ATOMIC_RELAXED, __HIP_MEMORY_SCOPE_AGENT);
}
__device__ __forceinline__ float sigm(float x){ return 1.0f/(1.0f+expf(-x)); }

// hierarchical 256-wg barrier: 16 groups x 16 -> root; poll root==16
__device__ __forceinline__ void gbarrier(char* wsb, int wid, int b){
  __syncthreads();
  if (threadIdx.x == 0){
    asm volatile("s_waitcnt vmcnt(0) lgkmcnt(0)" ::: "memory");
    unsigned* l1   = (unsigned*)(wsb + WS_ML1 + (size_t)(wid >> 4)*ML1_PAGE) + b;
    unsigned* root = (unsigned*)(wsb + WS_MROOT) + b;
    if (AU_ADD(l1) == 15u) AU_ADD(root);
    while (AU_LD(root) < 16u) __builtin_amdgcn_s_sleep(1);
    asm volatile("" ::: "memory");
  }
  __syncthreads();
}

// ---------------------------------------------------------------------------
// startup: feat[t][k] = Ws[k]·x[t] + bs[k]
__global__ __launch_bounds__(512) void feat_kernel(
    const float* __restrict__ x, const float* __restrict__ Ws,
    const float* __restrict__ bs, float* __restrict__ feat)
{
  __shared__ float s_x[16][360];
  __shared__ float s_w[512][20];
  const int bid = blockIdx.x, tid = threadIdx.x;
  const int t0 = bid * 16;
  for (int tt = 0; tt < 16; tt++)
    if (tid < 360) s_x[tt][tid] = x[(t0+tt)*360 + tid];
  float acc[16];
  #pragma unroll
  for (int i = 0; i < 16; i++) acc[i] = 0.f;
  for (int d0 = 0; d0 < 360; d0 += 16){
    const int dn = (360 - d0 < 16) ? (360 - d0) : 16;
    __syncthreads();
    if (dn == 16){
      #pragma unroll
      for (int c4 = 0; c4 < 4; c4++)
        *(float4*)&s_w[tid][c4*4] = *(const float4*)&Ws[tid*360 + d0 + c4*4];
    } else {
      for (int c = 0; c < dn; c++) s_w[tid][c] = Ws[tid*360 + d0 + c];
    }
    __syncthreads();
    for (int c = 0; c < dn; c++){
      float wv = s_w[tid][c];
      #pragma unroll
      for (int tt = 0; tt < 16; tt++) acc[tt] += wv * s_x[tt][d0 + c];
    }
  }
  for (int tt = 0; tt < 16; tt++)
    feat[(t0+tt)*512 + tid] = acc[tt] + bs[tid];
}

// ---------------------------------------------------------------------------
// post-pass: out[t] = out[t] - logsumexp(out[t])  (in place)
__global__ __launch_bounds__(64) void ls_kernel(float* __restrict__ out)
{
  const int t = blockIdx.x, l = threadIdx.x;
  float v[8];
  #pragma unroll
  for (int i = 0; i < 8; i++) v[i] = out[t*512 + l*8 + i];
  float m0 = v[0];
  #pragma unroll
  for (int i = 1; i < 8; i++) m0 = fmaxf(m0, v[i]);
  #pragma unroll
  for (int mk = 32; mk; mk >>= 1) m0 = fmaxf(m0, __shfl_xor(m0, mk));
  float s = 0.f;
  #pragma unroll
  for (int i = 0; i < 8; i++) s += expf(v[i] - m0);
  #pragma unroll
  for (int mk = 32; mk; mk >>= 1) s += __shfl_xor(s, mk);
  float lse = m0 + logf(s);
  #pragma unroll
  for (int i = 0; i < 8; i++) out[t*512 + l*8 + i] = v[i] - lse;
}

// ---------------------------------------------------------------------------
// persistent kernel: 256 wgs x 512 thr (8 waves). Wave w owns gate rows
// {2w, 2w+1}; lane l owns f4 col-chunks at dword 256*j + 4*l (bank-clean).
__global__ __launch_bounds__(512, 1) void lstm_persist(
    const float* __restrict__ Wih1, const float* __restrict__ Whh1,
    const float* __restrict__ Wih2, const float* __restrict__ Whh2,
    const float* __restrict__ Wl,   const float* __restrict__ Wm,
    const float* __restrict__ bih1, const float* __restrict__ bhh1,
    const float* __restrict__ bih2, const float* __restrict__ bhh2,
    const float* __restrict__ blp,  const float* __restrict__ bmp,
    char* __restrict__ wsb, float* __restrict__ out)
{
  extern __shared__ float smem[];
  float* s_in = smem;               // 2560: phase-A [feat|h1|h2], phase-B [h1|h2]
  float* wa   = smem + OFF_WA;      // [16][1024] = WCL rows (h2-block of gates1)
  float* wb   = smem + OFF_WB;      // [16][768]  = Whh2 cols 256..1023 (init: WCtmp)
  float* wy   = smem + OFF_WY;      // [2][1024]  = Wl rows wid*2, wid*2+1
  __shared__ float s_part[16];
  __shared__ float s_py[8];
  __shared__ float s_sums[32];

  float* h1b = (float*)(wsb + WS_H1);
  float* h2b = (float*)(wsb + WS_H2);
  const float* featp = (const float*)(wsb + WS_FEAT);

  const int wid = blockIdx.x, tid = threadIdx.x;
  const int w = tid >> 6, l = tid & 63;
  const int o0 = 2*w, o1 = 2*w + 1;
  const int rA0 = (o0 >> 2)*1024 + wid*4 + (o0 & 3);
  const int rA1 = (o1 >> 2)*1024 + wid*4 + (o1 & 3);

  // ===== init 1: stage this wg's 16 Wih1e rows (16x128) into s_in =====
  for (int idx = tid; idx < 2048; idx += 512){
    int o = idx >> 7, e = idx & 127;
    int r = (o >> 2)*1024 + wid*4 + (o & 3);
    s_in[idx] = Wih1[r*640 + 512 + e];
  }
  __syncthreads();

  // ===== init 2: WCtmp = Wih1e @ Wm  (16x512) -> wb area =====
  {
    float4 a00 = {0,0,0,0}, a01 = a00, a10 = a00, a11 = a00;
    for (int e = 0; e < 128; e++){
      float w0e = s_in[o0*128 + e], w1e = s_in[o1*128 + e];
      float4 m0 = *(const float4*)&Wm[e*512 + l*4];
      float4 m1 = *(const float4*)&Wm[e*512 + l*4 + 256];
      FMA4(a00, w0e, m0); FMA4(a01, w0e, m1);
      FMA4(a10, w1e, m0); FMA4(a11, w1e, m1);
    }
    *(float4*)&wb[o0*512 + l*4]       = a00;
    *(float4*)&wb[o0*512 + l*4 + 256] = a01;
    *(float4*)&wb[o1*512 + l*4]       = a10;
    *(float4*)&wb[o1*512 + l*4 + 256] = a11;
  }
  __syncthreads();

  // ===== init 3: WCL = WCtmp @ Wl (16x1024) -> wa; rowsum/bl piggyback =====
  {
    float4 c00={0,0,0,0}, c01=c00, c02=c00, c03=c00;
    float4 c10=c00, c11=c00, c12=c00, c13=c00;
    float rs0=0.f, rs1=0.f, wl0=0.f, wl1=0.f;
    for (int m = 0; m < 512; m++){
      float t0 = wb[o0*512 + m], t1 = wb[o1*512 + m];
      float blm = blp[m];
      rs0 += t0; wl0 += t0*blm; rs1 += t1; wl1 += t1*blm;
      float4 q0 = *(const float4*)&Wl[m*1024 + l*4];
      float4 q1 = *(const float4*)&Wl[m*1024 + l*4 + 256];
      float4 q2 = *(const float4*)&Wl[m*1024 + l*4 + 512];
      float4 q3 = *(const float4*)&Wl[m*1024 + l*4 + 768];
      FMA4(c00,t0,q0); FMA4(c01,t0,q1); FMA4(c02,t0,q2); FMA4(c03,t0,q3);
      FMA4(c10,t1,q0); FMA4(c11,t1,q1); FMA4(c12,t1,q2); FMA4(c13,t1,q3);
    }
    *(float4*)&wa[o0*1024 + l*4      ] = c00;
    *(float4*)&wa[o0*1024 + l*4 + 256] = c01;
    *(float4*)&wa[o0*1024 + l*4 + 512] = c02;
    *(float4*)&wa[o0*1024 + l*4 + 768] = c03;
    *(float4*)&wa[o1*1024 + l*4      ] = c10;
    *(float4*)&wa[o1*1024 + l*4 + 256] = c11;
    *(float4*)&wa[o1*1024 + l*4 + 512] = c12;
    *(float4*)&wa[o1*1024 + l*4 + 768] = c13;
    if (l == 0){
      s_sums[w*4+0] = rs0; s_sums[w*4+1] = rs1;
      s_sums[w*4+2] = wl0; s_sums[w*4+3] = wl1;
    }
  }
  __syncthreads();

  // ===== init 4: per-row bias regs (wave 0) =====
  float biasAreg=0.f, biasBreg=0.f, bE2reg=0.f, rsReg=0.f;
  float bl0=0.f, bl1=0.f, c1=0.f, c2=0.f;
  if (w == 0 && l < 16){
    int r = (l >> 2)*1024 + wid*4 + (l & 3);
    biasAreg = bih1[r] + bhh1[r];
    biasBreg = bih2[r] + bhh2[r];
    rsReg = s_sums[(l>>1)*4 + (l&1)];
    float acc = s_sums[(l>>1)*4 + 2 + (l&1)];
    for (int e = 0; e < 128; e++) acc += s_in[l*128 + e] * bmp[e];
    bE2reg = acc;
  }
  if (w == 0 && l == 0){ bl0 = blp[wid*2]; bl1 = blp[wid*2 + 1]; }

  // ===== init 5: LDS weights wb (Whh2 cols 256..1023) and wy (Wl rows) =====
  for (int o = 0; o < 16; o++){
    int r = (o >> 2)*1024 + wid*4 + (o & 3);
    for (int c = tid; c < 768; c += 512)
      wb[o*768 + c] = Whh2[r*1024 + 256 + c];
  }
  for (int idx = tid; idx < 2048; idx += 512){
    int row = idx >> 10, c = idx & 1023;
    wy[idx] = Wl[(wid*2 + row)*1024 + c];
  }

  // ===== init 6: pinned register weights (88 floats/thread) =====
  float4 wA0[6], wA1[6], wB0[5], wB1[5];
  #pragma unroll
  for (int j = 0; j < 6; j++){
    int c = 256*j + l*4;
    wA0[j] = (c < 512) ? *(const float4*)&Wih1[rA0*640 + c]
                       : *(const float4*)&Whh1[rA0*1024 + c - 512];
    wA1[j] = (c < 512) ? *(const float4*)&Wih1[rA1*640 + c]
                       : *(const float4*)&Whh1[rA1*1024 + c - 512];
  }
  #pragma unroll
  for (int j = 0; j < 5; j++){
    int c = 256*j + l*4;
    wB0[j] = (c < 1024) ? *(const float4*)&Wih2[rA0*1024 + c]
                        : *(const float4*)&Whh2[rA0*1024 + c - 1024];
    wB1[j] = (c < 1024) ? *(const float4*)&Wih2[rA1*1024 + c]
                        : *(const float4*)&Whh2[rA1*1024 + c - 1024];
  }
  #pragma unroll
  for (int j = 0; j < 6; j++){ PIN4(wA0[j]); PIN4(wA1[j]); }
  #pragma unroll
  for (int j = 0; j < 5; j++){ PIN4(wB0[j]); PIN4(wB1[j]); }
  PIN1(biasAreg); PIN1(biasBreg); PIN1(bE2reg); PIN1(rsReg);
  PIN1(bl0); PIN1(bl1);
  __syncthreads();

  // ===== main loop =====
  for (int t = 0; t < T_STEPS; t++){
    const int rb = t & 1, wbuf = (t + 1) & 1;

    // ---- phase A stage: s_in = [feat(512) | h1(1024) | h2(1024)] ----
    {
      int s1 = tid*2;
      float2 v1 = (s1 < 512) ? *(const float2*)&featp[t*512 + s1]
                             : AL2(&h1b[rb*1024 + s1 - 512]);
      *(float2*)&s_in[s1] = v1;
      int s2 = 1024 + tid*2;
      float2 v2 = (tid < 256) ? AL2(&h1b[rb*1024 + s2 - 512])
                              : AL2(&h2b[rb*1024 + s2 - 1536]);
      *(float2*)&s_in[s2] = v2;
      if (tid < 256)
        *(float2*)&s_in[2048 + tid*2] = AL2(&h2b[rb*1024 + 512 + tid*2]);
    }
    __syncthreads();

    // ---- y(t-1) rows (overlap): waves 0-3 row wid*2, waves 4-7 row wid*2+1
    if (t > 0){
      int yrow = w >> 2, cb = (w & 3)*256 + l*4;
      float4 xv = *(float4*)&s_in[1536 + cb];
      float4 wv = *(float4*)&wy[yrow*1024 + cb];
      float yp = DOT4(wv, xv);
      #pragma unroll
      for (int mk = 32; mk; mk >>= 1) yp += __shfl_xor(yp, mk);
      if (l == 0) s_py[w] = yp;
    }
    __syncthreads();
    if (t > 0 && w == 0 && l == 0){
      float y0 = s_py[0]+s_py[1]+s_py[2]+s_py[3] + bl0;
      float y1 = s_py[4]+s_py[5]+s_py[6]+s_py[7] + bl1;
      AS(&out[(t-1)*512 + wid*2    ], y0);
      AS(&out[(t-1)*512 + wid*2 + 1], y1);
      asm volatile("s_waitcnt vmcnt(0)" ::: "memory");
      unsigned* yl1 = (unsigned*)(wsb + WS_YL1 + (size_t)(wid >> 4)*YL1_PAGE) + (t-1);
      if (AU_ADD(yl1) == 15u) AU_ADD((unsigned*)(wsb + WS_YROOT) + (t-1));
    }

    // ---- gates1 dot: regs j=0..5 (feat|h1) + LDS k=0..3 (WCL @ h2) ----
    float acc0 = 0.f, acc1 = 0.f;
    #pragma unroll
    for (int j = 0; j < 6; j++){
      float4 xv = *(float4*)&s_in[256*j + l*4];
      acc0 += DOT4(wA0[j], xv); acc1 += DOT4(wA1[j], xv);
    }
    #pragma unroll
    for (int k = 0; k < 4; k++){
      float4 xv = *(float4*)&s_in[1536 + 256*k + l*4];
      float4 u0 = *(float4*)&wa[o0*1024 + 256*k + l*4];
      float4 u1 = *(float4*)&wa[o1*1024 + 256*k + l*4];
      acc0 += DOT4(u0, xv); acc1 += DOT4(u1, xv);
    }
    #pragma unroll
    for (int mk = 32; mk; mk >>= 1){
      acc0 += __shfl_xor(acc0, mk); acc1 += __shfl_xor(acc1, mk);
    }
    if (l == 0){ s_part[o0] = acc0; s_part[o1] = acc1; }
    __syncthreads();

    // ---- lse(t-1): wave 0 gathers the 512 published y values ----
    float lse = 0.f;
    if (w == 0 && t > 0){
      unsigned* yroot = (unsigned*)(wsb + WS_YROOT) + (t-1);
      while (AU_LD(yroot) < 16u) __builtin_amdgcn_s_sleep(1);
      const float* yrow = &out[(t-1)*512];
      float v0 = AL(&yrow[l*8+0]), v1 = AL(&yrow[l*8+1]);
      float v2 = AL(&yrow[l*8+2]), v3 = AL(&yrow[l*8+3]);
      float v4 = AL(&yrow[l*8+4]), v5 = AL(&yrow[l*8+5]);
      float v6 = AL(&yrow[l*8+6]), v7 = AL(&yrow[l*8+7]);
      float m0 = fmaxf(fmaxf(fmaxf(v0,v1), fmaxf(v2,v3)),
                       fmaxf(fmaxf(v4,v5), fmaxf(v6,v7)));
      #pragma unroll
      for (int mk = 32; mk; mk >>= 1) m0 = fmaxf(m0, __shfl_xor(m0, mk));
      float s = expf(v0-m0)+expf(v1-m0)+expf(v2-m0)+expf(v3-m0)
              + expf(v4-m0)+expf(v5-m0)+expf(v6-m0)+expf(v7-m0);
      #pragma unroll
      for (int mk = 32; mk; mk >>= 1) s += __shfl_xor(s, mk);
      lse = m0 + logf(s);
    }
    if (w == 0 && l < 16){
      float sum = s_part[l] + biasAreg;
      if (t > 0) sum += bE2reg - rsReg*lse;
      float gi = __shfl(sum, (l & 3));
      float gf = __shfl(sum, 4 + (l & 3));
      float gg = __shfl(sum, 8 + (l & 3));
      float go = __shfl(sum, 12 + (l & 3));
      if (l < 4){
        float cn = sigm(gf)*c1 + sigm(gi)*tanhf(gg);
        c1 = cn;
        AS(&h1b[wbuf*1024 + wid*4 + l], sigm(go)*tanhf(cn));
      }
    }
    gbarrier(wsb, wid, t*2 + 0);

    // ---- phase B stage: s_in = [h1_new(1024) | h2_old(1024)] ----
    {
      int s1 = tid*2;
      *(float2*)&s_in[s1]        = AL2(&h1b[wbuf*1024 + s1]);
      *(float2*)&s_in[1024 + s1] = AL2(&h2b[rb*1024 + s1]);
    }
    __syncthreads();

    // ---- gates2 dot: regs j=0..4 + LDS k=0..2 (Whh2 cols 256..1023) ----
    float b0 = 0.f, b1 = 0.f;
    #pragma unroll
    for (int j = 0; j < 5; j++){
      float4 xv = *(float4*)&s_in[256*j + l*4];
      b0 += DOT4(wB0[j], xv); b1 += DOT4(wB1[j], xv);
    }
    #pragma unroll
    for (int k = 0; k < 3; k++){
      float4 xv = *(float4*)&s_in[1280 + 256*k + l*4];
      float4 u0 = *(float4*)&wb[o0*768 + 256*k + l*4];
      float4 u1 = *(float4*)&wb[o1*768 + 256*k + l*4];
      b0 += DOT4(u0, xv); b1 += DOT4(u1, xv);
    }
    #pragma unroll
    for (int mk = 32; mk; mk >>= 1){
      b0 += __shfl_xor(b0, mk); b1 += __shfl_xor(b1, mk);
    }
    if (l == 0){ s_part[o0] = b0; s_part[o1] = b1; }
    __syncthreads();
    if (w == 0 && l < 16){
      float sum = s_part[l] + biasBreg;
      float gi = __shfl(sum, (l & 3));
      float gf = __shfl(sum, 4 + (l & 3));
      float gg = __shfl(sum, 8 + (l & 3));
      float go = __shfl(sum, 12 + (l & 3));
      if (l < 4){
        float cn = sigm(gf)*c2 + sigm(gi)*tanhf(gg);
        c2 = cn;
        AS(&h2b[wbuf*1024 + wid*4 + l], sigm(go)*tanhf(cn));
      }
    }
    gbarrier(wsb, wid, t*2 + 1);
  }

  // ===== tail: y(T-1) from final h2 (buffer 0) =====
  *(float2*)&s_in[1536 + tid*2] = AL2(&h2b[tid*2]);
  __syncthreads();
  {
    int yrow = w >> 2, cb = (w & 3)*256 + l*4;
    float4 xv = *(float4*)&s_in[1536 + cb];
    float4 wv = *(float4*)&wy[yrow*1024 + cb];
    float yp = DOT4(wv, xv);
    #pragma unroll
    for (int mk = 32; mk; mk >>= 1) yp += __shfl_xor(yp, mk);
    if (l == 0) s_py[w] = yp;
  }
  __syncthreads();
  if (w == 0 && l == 0){
    out[(T_STEPS-1)*512 + wid*2    ] = s_py[0]+s_py[1]+s_py[2]+s_py[3] + bl0;
    out[(T_STEPS-1)*512 + wid*2 + 1] = s_py[4]+s_py[5]+s_py[6]+s_py[7] + bl1;
  }
}

// ---------------------------------------------------------------------------
extern "C" void kernel_launch(void* const* d_in, const int* in_sizes, int n_in,
                              void* d_out, int out_size, void* d_ws, size_t ws_size,
                              hipStream_t stream)
{
  const float* x    = (const float*)d_in[0];
  const float* Ws   = (const float*)d_in[1];
  const float* bs   = (const float*)d_in[2];
  const float* Wih1 = (const float*)d_in[3];
  const float* Whh1 = (const float*)d_in[4];
  const float* bih1 = (const float*)d_in[5];
  const float* bhh1 = (const float*)d_in[6];
  const float* Wih2 = (const float*)d_in[7];
  const float* Whh2 = (const float*)d_in[8];
  const float* bih2 = (const float*)d_in[9];
  const float* bhh2 = (const float*)d_in[10];
  const float* Wl   = (const float*)d_in[11];
  const float* bl   = (const float*)d_in[12];
  const float* Wm   = (const float*)d_in[13];
  const float* bm   = (const float*)d_in[14];
  char* wsb  = (char*)d_ws;
  float* out = (float*)d_out;

  // zero barrier counters + recurrent state (fresh each call / graph replay)
  hipMemsetAsync(wsb, 0, WS_ZERO_BYTES, stream);

  feat_kernel<<<256, 512, 0, stream>>>(x, Ws, bs, (float*)(wsb + WS_FEAT));
  lstm_persist<<<NWG, 512, SMEM_BYTES, stream>>>(
      Wih1, Whh1, Wih2, Whh2, Wl, Wm,
      bih1, bhh1, bih2, bhh2, bl, bm, wsb, out);
  ls_kernel<<<T_STEPS, 64, 0, stream>>>(out);
}